// Round 2
// baseline (11040.041 us; speedup 1.0000x reference)
//
#include <hip/hip_runtime.h>
#include <hip/hip_bf16.h>
#include <math.h>

#define HDIM 1024
#define NHEAD 16
#define HEADD 64
#define FFDIM 4096
#define NLAYERS 4
#define VOCAB 32000
#define NBATCH 2
#define SEQLEN 1024
#define NTOK (NBATCH * SEQLEN)

// h[tok,d] = emb[x[tok],d] + pe(batch(tok), d)   -- pe indexed by BATCH (faithful quirk)
__global__ void embed_kernel(const int* __restrict__ x, const float* __restrict__ emb,
                             float* __restrict__ h) {
  const int tok = blockIdx.x;
  const int b = tok >> 10;  // SEQLEN = 1024
  const int row = x[tok];
  const float c = -9.210340371976184f / (float)HDIM;  // -ln(10000)/H
#pragma unroll
  for (int i = 0; i < 4; i++) {
    const int d = threadIdx.x + (i << 8);
    const float ang = (float)b * expf(c * (float)(d & ~1));
    const float pe = (d & 1) ? cosf(ang) : sinf(ang);
    h[(size_t)tok * HDIM + d] = emb[(size_t)row * HDIM + d] + pe;
  }
}

// C[M,N] = A[M,K] * W[K,N] + bias[N]; optional ReLU. All fp32.
// 64x64 tile, 256 threads, 4x4 per thread, K-chunk 16. LDS stored [k][m]/[k][n]
// (pad 68 -> 272B row stride keeps float4 LDS reads 16B-aligned => ds_read_b128).
template <bool RELU>
__global__ void gemm_kernel(const float* __restrict__ A, const float* __restrict__ W,
                            const float* __restrict__ bias, float* __restrict__ C,
                            const int M, const int N, const int K) {
  __shared__ float As[16][68];  // [k][m]
  __shared__ float Ws[16][68];  // [k][n]
  const int t = threadIdx.x;
  const int bn = blockIdx.x, bm = blockIdx.y;
  const int tn = t & 15, tm = t >> 4;
  const int lrow = t >> 2, lk0 = (t & 3) << 2;  // A-tile load: row 0..63, 4 consecutive k
  const int wk = t >> 4, wn0 = (t & 15) << 2;   // W-tile load: k 0..15, 4 consecutive n
  float acc[4][4];
#pragma unroll
  for (int i = 0; i < 4; i++)
#pragma unroll
    for (int j = 0; j < 4; j++) acc[i][j] = 0.f;

  const float* Arow = A + (size_t)(bm * 64 + lrow) * K + lk0;
  const float* Wrow = W + (size_t)wk * N + bn * 64 + wn0;

  for (int kk = 0; kk < K; kk += 16) {
    const float4 av = *(const float4*)(Arow + kk);
    As[lk0 + 0][lrow] = av.x;
    As[lk0 + 1][lrow] = av.y;
    As[lk0 + 2][lrow] = av.z;
    As[lk0 + 3][lrow] = av.w;
    *(float4*)&Ws[wk][wn0] = *(const float4*)(Wrow + (size_t)kk * N);
    __syncthreads();
#pragma unroll
    for (int k = 0; k < 16; k++) {
      const float4 a = *(const float4*)&As[k][tm << 2];
      const float4 w = *(const float4*)&Ws[k][tn << 2];
      acc[0][0] += a.x * w.x; acc[0][1] += a.x * w.y; acc[0][2] += a.x * w.z; acc[0][3] += a.x * w.w;
      acc[1][0] += a.y * w.x; acc[1][1] += a.y * w.y; acc[1][2] += a.y * w.z; acc[1][3] += a.y * w.w;
      acc[2][0] += a.z * w.x; acc[2][1] += a.z * w.y; acc[2][2] += a.z * w.z; acc[2][3] += a.z * w.w;
      acc[3][0] += a.w * w.x; acc[3][1] += a.w * w.y; acc[3][2] += a.w * w.z; acc[3][3] += a.w * w.w;
    }
    __syncthreads();
  }

  float bb[4];
#pragma unroll
  for (int j = 0; j < 4; j++) bb[j] = bias[bn * 64 + (tn << 2) + j];
  const size_t cbase = (size_t)(bm * 64 + (tm << 2)) * N + bn * 64 + (tn << 2);
#pragma unroll
  for (int i = 0; i < 4; i++) {
#pragma unroll
    for (int j = 0; j < 4; j++) {
      float v = acc[i][j] + bb[j];
      if (RELU) v = fmaxf(v, 0.f);
      C[cbase + (size_t)i * N + j] = v;
    }
  }
}

// One block per (b, head, 8 query rows). q/k/v/o are [B,S,H] fp32, head n uses cols n*64..+63.
__global__ void attn_kernel(const float* __restrict__ q, const float* __restrict__ k,
                            const float* __restrict__ v, float* __restrict__ o) {
  const int qb = blockIdx.x, nh = blockIdx.y, b = blockIdx.z;
  const int t = threadIdx.x;
  __shared__ float qs[8][HEADD];
  __shared__ float sc[SEQLEN];
  __shared__ float red[4];
  __shared__ float ored[4][HEADD];
  const size_t bbase = (size_t)b * SEQLEN * HDIM + nh * HEADD;
  const float* kb = k + bbase;
  const float* vb = v + bbase;
  for (int idx = t; idx < 8 * HEADD; idx += 256) {
    const int qq = idx >> 6, d = idx & 63;
    qs[qq][d] = q[bbase + (size_t)(qb * 8 + qq) * HDIM + d];
  }
  __syncthreads();
  for (int qq = 0; qq < 8; qq++) {
    // scores = q . k * 1/sqrt(64)
    for (int j = t; j < SEQLEN; j += 256) {
      const float* kr = kb + (size_t)j * HDIM;
      float s = 0.f;
#pragma unroll
      for (int d = 0; d < HEADD; d++) s += qs[qq][d] * kr[d];
      sc[j] = s * 0.125f;
    }
    __syncthreads();
    // block max
    float m = -1e30f;
    for (int j = t; j < SEQLEN; j += 256) m = fmaxf(m, sc[j]);
#pragma unroll
    for (int off = 32; off > 0; off >>= 1) m = fmaxf(m, __shfl_xor(m, off));
    if ((t & 63) == 0) red[t >> 6] = m;
    __syncthreads();
    m = fmaxf(fmaxf(red[0], red[1]), fmaxf(red[2], red[3]));
    __syncthreads();  // everyone has read red before it is rewritten
    // exp + sum
    float s = 0.f;
    for (int j = t; j < SEQLEN; j += 256) {
      const float e = expf(sc[j] - m);
      sc[j] = e;
      s += e;
    }
#pragma unroll
    for (int off = 32; off > 0; off >>= 1) s += __shfl_xor(s, off);
    if ((t & 63) == 0) red[t >> 6] = s;
    __syncthreads();
    const float inv = 1.f / (red[0] + red[1] + red[2] + red[3]);
    // o[d] = sum_j p_j * v[j][d]; thread (jb,d) does 256 j's, coalesced over d
    const int d = t & 63, jb = t >> 6;
    float part = 0.f;
    const float* vp = vb + (size_t)(jb * 256) * HDIM + d;
    for (int j = 0; j < 256; j++) part += sc[jb * 256 + j] * vp[(size_t)j * HDIM];
    ored[jb][d] = part;
    __syncthreads();
    if (t < HEADD) {
      o[bbase + (size_t)(qb * 8 + qq) * HDIM + t] =
          (ored[0][t] + ored[1][t] + ored[2][t] + ored[3][t]) * inv;
    }
    __syncthreads();
  }
}

// h = LayerNorm(h + t_in) * g + b   (one block per token, H=1024, 4 elems/thread)
__global__ void ln_kernel(float* __restrict__ h, const float* __restrict__ t_in,
                          const float* __restrict__ g, const float* __restrict__ bta) {
  const int tok = blockIdx.x;
  const int t = threadIdx.x;
  __shared__ float red[8];
  float r[4];
  float s = 0.f;
  const size_t base = (size_t)tok * HDIM;
#pragma unroll
  for (int i = 0; i < 4; i++) {
    const int d = t + (i << 8);
    r[i] = h[base + d] + t_in[base + d];
    s += r[i];
  }
#pragma unroll
  for (int off = 32; off > 0; off >>= 1) s += __shfl_xor(s, off);
  if ((t & 63) == 0) red[t >> 6] = s;
  __syncthreads();
  const float mean = (red[0] + red[1] + red[2] + red[3]) * (1.f / HDIM);
  float vs = 0.f;
#pragma unroll
  for (int i = 0; i < 4; i++) {
    const float dv = r[i] - mean;
    vs += dv * dv;
  }
#pragma unroll
  for (int off = 32; off > 0; off >>= 1) vs += __shfl_xor(vs, off);
  if ((t & 63) == 0) red[4 + (t >> 6)] = vs;
  __syncthreads();
  const float var = (red[4] + red[5] + red[6] + red[7]) * (1.f / HDIM);
  const float inv = 1.f / sqrtf(var + 1e-5f);
#pragma unroll
  for (int i = 0; i < 4; i++) {
    const int d = t + (i << 8);
    h[base + d] = (r[i] - mean) * inv * g[d] + bta[d];
  }
}

extern "C" void kernel_launch(void* const* d_in, const int* in_sizes, int n_in,
                              void* d_out, int out_size, void* d_ws, size_t ws_size,
                              hipStream_t stream) {
  const int* x = (const int*)d_in[0];
  const float* emb = (const float*)d_in[1];
  const float* Wq = (const float*)d_in[2];
  const float* bq = (const float*)d_in[3];
  const float* Wk = (const float*)d_in[4];
  const float* bk = (const float*)d_in[5];
  const float* Wv = (const float*)d_in[6];
  const float* bv = (const float*)d_in[7];
  const float* Wo = (const float*)d_in[8];
  const float* bo = (const float*)d_in[9];
  const float* ln1g = (const float*)d_in[10];
  const float* ln1b = (const float*)d_in[11];
  const float* W1 = (const float*)d_in[12];
  const float* b1 = (const float*)d_in[13];
  const float* W2 = (const float*)d_in[14];
  const float* b2 = (const float*)d_in[15];
  const float* ln2g = (const float*)d_in[16];
  const float* ln2b = (const float*)d_in[17];
  const float* fcw = (const float*)d_in[18];
  const float* fcb = (const float*)d_in[19];

  float* h = (float*)d_ws;
  const size_t TH = (size_t)NTOK * HDIM;  // 2M floats
  float* qb = h + TH;
  float* kb = qb + TH;
  float* vb = kb + TH;
  float* ob = vb + TH;
  float* tb = ob + TH;
  float* ffb = tb + TH;  // NTOK * FFDIM floats

  embed_kernel<<<NTOK, 256, 0, stream>>>(x, emb, h);

  const dim3 gHH(HDIM / 64, NTOK / 64);
  const dim3 gHF(FFDIM / 64, NTOK / 64);
  const dim3 gHV(VOCAB / 64, NTOK / 64);
  for (int l = 0; l < NLAYERS; l++) {
    const size_t wHH = (size_t)l * HDIM * HDIM;
    gemm_kernel<false><<<gHH, 256, 0, stream>>>(h, Wq + wHH, bq + l * HDIM, qb, NTOK, HDIM, HDIM);
    gemm_kernel<false><<<gHH, 256, 0, stream>>>(h, Wk + wHH, bk + l * HDIM, kb, NTOK, HDIM, HDIM);
    gemm_kernel<false><<<gHH, 256, 0, stream>>>(h, Wv + wHH, bv + l * HDIM, vb, NTOK, HDIM, HDIM);
    attn_kernel<<<dim3(SEQLEN / 8, NHEAD, NBATCH), 256, 0, stream>>>(qb, kb, vb, ob);
    gemm_kernel<false><<<gHH, 256, 0, stream>>>(ob, Wo + wHH, bo + l * HDIM, tb, NTOK, HDIM, HDIM);
    ln_kernel<<<NTOK, 256, 0, stream>>>(h, tb, ln1g + l * HDIM, ln1b + l * HDIM);
    gemm_kernel<true><<<gHF, 256, 0, stream>>>(h, W1 + (size_t)l * HDIM * FFDIM, b1 + l * FFDIM,
                                               ffb, NTOK, FFDIM, HDIM);
    gemm_kernel<false><<<gHH, 256, 0, stream>>>(ffb, W2 + (size_t)l * FFDIM * HDIM, b2 + l * HDIM,
                                                tb, NTOK, HDIM, FFDIM);
    ln_kernel<<<NTOK, 256, 0, stream>>>(h, tb, ln2g + l * HDIM, ln2b + l * HDIM);
  }
  gemm_kernel<false><<<gHV, 256, 0, stream>>>(h, fcw, fcb, (float*)d_out, NTOK, VOCAB, HDIM);
}